// Round 1
// baseline (366.563 us; speedup 1.0000x reference)
//
#include <hip/hip_runtime.h>
#include <hip/hip_fp16.h>

typedef unsigned short ushort_t;
typedef __attribute__((ext_vector_type(8))) _Float16 half8v;
typedef __attribute__((ext_vector_type(4))) float float4v;
typedef __attribute__((ext_vector_type(8))) unsigned short ushort8v;

#define DEV_INLINE __device__ __forceinline__

DEV_INLINE ushort_t f2h_bits(float f) {
  return __half_as_ushort(__float2half(f));
}

// ---------------- router: logits, softmax max, argmax ----------------
__global__ __launch_bounds__(256) void router_kernel(
    const float* __restrict__ x, const float* __restrict__ rw,
    int* __restrict__ idx, float* __restrict__ gate)
{
  constexpr int D = 1024, E = 8;
  int token = (int)((blockIdx.x * 256 + threadIdx.x) >> 6);
  int lane = threadIdx.x & 63;
  const float* xr = x + (size_t)token * D;
  float acc[E];
#pragma unroll
  for (int e = 0; e < E; ++e) acc[e] = 0.f;
  for (int d = lane; d < D; d += 64) {
    float xv = xr[d];
#pragma unroll
    for (int e = 0; e < E; ++e) acc[e] += xv * rw[d * E + e];
  }
#pragma unroll
  for (int off = 32; off >= 1; off >>= 1) {
#pragma unroll
    for (int e = 0; e < E; ++e) acc[e] += __shfl_xor(acc[e], off);
  }
  if (lane == 0) {
    float m = acc[0]; int am = 0;
#pragma unroll
    for (int e = 1; e < E; ++e) { if (acc[e] > m) { m = acc[e]; am = e; } }
    float s = 0.f;
#pragma unroll
    for (int e = 0; e < E; ++e) s += __expf(acc[e] - m);
    idx[token] = am;
    gate[token] = 1.0f / s;   // = max(softmax)
  }
}

// ---------------- scan: token -> slot (capacity C), slot -> token ----------------
__global__ __launch_bounds__(1024) void scan_kernel(
    const int* __restrict__ idx, const float* __restrict__ gate,
    int* __restrict__ slotmap, float* __restrict__ gate_slot)
{
  constexpr int C = 1024, E = 8;
  __shared__ unsigned long long s0[1024];
  __shared__ unsigned long long s1[1024];
  int tid = threadIdx.x;
  int myidx[8];
  unsigned long long c0 = 0, c1 = 0;
#pragma unroll
  for (int j = 0; j < 8; ++j) {
    int e = idx[tid * 8 + j];
    myidx[j] = e;
    if (e < 4) c0 += 1ull << (16 * e);
    else       c1 += 1ull << (16 * (e - 4));
  }
  s0[tid] = c0; s1[tid] = c1;
  __syncthreads();
  for (int off = 1; off < 1024; off <<= 1) {
    unsigned long long b0 = 0, b1 = 0;
    if (tid >= off) { b0 = s0[tid - off]; b1 = s1[tid - off]; }
    __syncthreads();
    s0[tid] += b0; s1[tid] += b1;
    __syncthreads();
  }
  unsigned long long p0 = s0[tid] - c0, p1 = s1[tid] - c1; // exclusive prefix
  unsigned long long t0 = s0[1023], t1 = s1[1023];         // totals
  int cnt[E];
#pragma unroll
  for (int e = 0; e < 4; ++e) {
    cnt[e]     = (int)((p0 >> (16 * e)) & 0xFFFF);
    cnt[4 + e] = (int)((p1 >> (16 * e)) & 0xFFFF);
  }
#pragma unroll
  for (int j = 0; j < 8; ++j) {
    int t = tid * 8 + j;
    int e = myidx[j];
    int pos = cnt[e]++;
    if (pos < C) {
      slotmap[e * C + pos] = t;
      gate_slot[e * C + pos] = gate[t];
    }
  }
  int total[E];
#pragma unroll
  for (int e = 0; e < 4; ++e) {
    total[e]     = (int)((t0 >> (16 * e)) & 0xFFFF);
    total[4 + e] = (int)((t1 >> (16 * e)) & 0xFFFF);
  }
  for (int s = tid; s < E * C; s += 1024) {
    int e = s / C, c = s % C;
    if (c >= total[e]) { slotmap[s] = -1; gate_slot[s] = 0.f; }
  }
}

// ---------------- gather x -> Xe (fp16), zeros for empty slots ----------------
__global__ __launch_bounds__(256) void gather_kernel(
    const float* __restrict__ x, const int* __restrict__ slotmap,
    ushort_t* __restrict__ Xe)
{
  constexpr int D = 1024;
  int slot = blockIdx.x;
  int t = slotmap[slot];
  int tid = threadIdx.x;
  ushort4* dst = (ushort4*)(Xe + (size_t)slot * D);
  ushort4 o;
  if (t >= 0) {
    float4 v = ((const float4*)(x + (size_t)t * D))[tid];
    o.x = f2h_bits(v.x); o.y = f2h_bits(v.y); o.z = f2h_bits(v.z); o.w = f2h_bits(v.w);
  } else {
    o.x = 0; o.y = 0; o.z = 0; o.w = 0;
  }
  dst[tid] = o;
}

// ---------------- transpose + fp32->fp16 convert: in [R][Cc] -> out [Cc][R] ----------------
__global__ __launch_bounds__(256) void transpose_cvt(
    const float* __restrict__ in, ushort_t* __restrict__ out, int R, int Cc)
{
  __shared__ ushort_t tile[64][65];
  size_t base = (size_t)blockIdx.z * (size_t)R * (size_t)Cc;
  int c0 = blockIdx.x * 64, r0 = blockIdx.y * 64;
  int tx = threadIdx.x & 63, ty = threadIdx.x >> 6;
#pragma unroll
  for (int i = 0; i < 16; ++i) {
    int r = ty + 4 * i;
    tile[r][tx] = f2h_bits(in[base + (size_t)(r0 + r) * Cc + c0 + tx]);
  }
  __syncthreads();
#pragma unroll
  for (int i = 0; i < 2; ++i) {
    int chunk = (int)threadIdx.x + i * 256;
    int c = chunk >> 3, g = chunk & 7;
    ushort8v v;
#pragma unroll
    for (int j = 0; j < 8; ++j) v[j] = tile[8 * g + j][c];
    *(ushort8v*)(out + base + (size_t)(c0 + c) * R + r0 + 8 * g) = v;
  }
}

// ---------------- grouped GEMM: C = A(f16,[M][K]) * Bt(f16,[N][K])^T ----------------
// MODE 0: H = relu(C + b1)  -> fp16 [E][M][N]
// MODE 1: out[token] = (C + b2) * gate, scattered via slotmap
template<int M_, int N_, int K_, int MODE>
__global__ __launch_bounds__(256) void gemm_bt(
    const ushort_t* __restrict__ A, const ushort_t* __restrict__ Bt,
    const float* __restrict__ bias,
    ushort_t* __restrict__ Hout, float* __restrict__ outp,
    const int* __restrict__ slotmap, const float* __restrict__ gate_slot)
{
  constexpr int BK = 64;
  __shared__ __attribute__((aligned(16))) ushort_t lA[128 * BK];
  __shared__ __attribute__((aligned(16))) ushort_t lB[128 * BK];
  const int e  = blockIdx.y;
  const int mt = blockIdx.x % (M_ / 128);
  const int nt = blockIdx.x / (M_ / 128);
  const ushort_t* Ae = A  + (size_t)e * M_ * K_ + (size_t)(mt * 128) * K_;
  const ushort_t* Be = Bt + (size_t)e * N_ * K_ + (size_t)(nt * 128) * K_;
  const int tid = threadIdx.x;
  const int lane = tid & 63;
  const int w = tid >> 6;
  const int wr = w >> 1, wc = w & 1;

  float4v acc[4][4] = {};

  for (int k0 = 0; k0 < K_; k0 += BK) {
#pragma unroll
    for (int j = 0; j < 4; ++j) {
      const int chunk = w * 4 + j;              // 16 chunks of 1KB per tile
      const int u = chunk * 64 + lane;          // 16B unit id, 0..1023
      const int r = u >> 3, inner = u & 7;
      const ushort_t* ga = Ae + (size_t)r * K_ + k0 + inner * 8;
      const ushort_t* gb = Be + (size_t)r * K_ + k0 + inner * 8;
      __builtin_amdgcn_global_load_lds(
          (const __attribute__((address_space(1))) void*)ga,
          (__attribute__((address_space(3))) void*)(lA + chunk * 512), 16, 0, 0);
      __builtin_amdgcn_global_load_lds(
          (const __attribute__((address_space(1))) void*)gb,
          (__attribute__((address_space(3))) void*)(lB + chunk * 512), 16, 0, 0);
    }
    __syncthreads();   // compiler drains vmcnt before s_barrier
#pragma unroll
    for (int kk = 0; kk < 2; ++kk) {
      half8v a[4], b[4];
#pragma unroll
      for (int i = 0; i < 4; ++i)
        a[i] = *(const half8v*)(lA + (wr * 64 + i * 16 + (lane & 15)) * BK + kk * 32 + (lane >> 4) * 8);
#pragma unroll
      for (int j = 0; j < 4; ++j)
        b[j] = *(const half8v*)(lB + (wc * 64 + j * 16 + (lane & 15)) * BK + kk * 32 + (lane >> 4) * 8);
#pragma unroll
      for (int i = 0; i < 4; ++i)
#pragma unroll
        for (int j = 0; j < 4; ++j)
          acc[i][j] = __builtin_amdgcn_mfma_f32_16x16x32_f16(a[i], b[j], acc[i][j], 0, 0, 0);
    }
    __syncthreads();
  }

  // C/D frag mapping: col = lane&15, row = (lane>>4)*4 + q
  const int lr = lane >> 4;
  const int lc = lane & 15;
  const int mrow_base = mt * 128 + wr * 64;
  const int ncol_base = nt * 128 + wc * 64;

  if (MODE == 0) {
    ushort_t* He = Hout + (size_t)e * M_ * N_;
#pragma unroll
    for (int i = 0; i < 4; ++i) {
#pragma unroll
      for (int j = 0; j < 4; ++j) {
        int n = ncol_base + j * 16 + lc;
        float bv = bias[e * N_ + n];
#pragma unroll
        for (int q = 0; q < 4; ++q) {
          int m = mrow_base + i * 16 + lr * 4 + q;
          float v = acc[i][j][q] + bv;
          v = v > 0.f ? v : 0.f;
          He[(size_t)m * N_ + n] = f2h_bits(v);
        }
      }
    }
  } else {
#pragma unroll
    for (int i = 0; i < 4; ++i) {
      int mbase = mrow_base + i * 16 + lr * 4;
#pragma unroll
      for (int q = 0; q < 4; ++q) {
        int slot = e * M_ + mbase + q;
        int t = slotmap[slot];
        if (t < 0) continue;
        float gt = gate_slot[slot];
#pragma unroll
        for (int j = 0; j < 4; ++j) {
          int n = ncol_base + j * 16 + lc;
          float v = (acc[i][j][q] + bias[e * N_ + n]) * gt;
          outp[(size_t)t * N_ + n] = v;
        }
      }
    }
  }
}

extern "C" void kernel_launch(void* const* d_in, const int* in_sizes, int n_in,
                              void* d_out, int out_size, void* d_ws, size_t ws_size,
                              hipStream_t stream)
{
  const float* x  = (const float*)d_in[0];
  const float* rw = (const float*)d_in[1];
  const float* w1 = (const float*)d_in[2];
  const float* b1 = (const float*)d_in[3];
  const float* w2 = (const float*)d_in[4];
  const float* b2 = (const float*)d_in[5];
  float* out = (float*)d_out;

  constexpr int D = 1024, E = 8, F = 4096, T = 8192, C = 1024;

  char* p = (char*)d_ws;
  auto take = [&](size_t bytes) { char* r = p; p += (bytes + 255) & ~(size_t)255; return r; };
  ushort_t* w1t = (ushort_t*)take((size_t)E * D * F * 2);  // [E][F][D] f16
  ushort_t* w2t = (ushort_t*)take((size_t)E * F * D * 2);  // [E][D][F] f16
  ushort_t* Xe  = (ushort_t*)take((size_t)E * C * D * 2);  // [E][C][D] f16
  ushort_t* H   = (ushort_t*)take((size_t)E * C * F * 2);  // [E][C][F] f16
  int*      idx = (int*)take((size_t)T * 4);
  float*   gate = (float*)take((size_t)T * 4);
  int*  slotmap = (int*)take((size_t)E * C * 4);
  float* gate_slot = (float*)take((size_t)E * C * 4);

  router_kernel<<<T / 4, 256, 0, stream>>>(x, rw, idx, gate);
  scan_kernel<<<1, 1024, 0, stream>>>(idx, gate, slotmap, gate_slot);
  gather_kernel<<<E * C, 256, 0, stream>>>(x, slotmap, Xe);
  transpose_cvt<<<dim3(F / 64, D / 64, E), 256, 0, stream>>>(w1, w1t, D, F); // [D][F]->[F][D]
  transpose_cvt<<<dim3(D / 64, F / 64, E), 256, 0, stream>>>(w2, w2t, F, D); // [F][D]->[D][F]
  hipMemsetAsync(d_out, 0, (size_t)out_size * sizeof(float), stream);
  // GEMM1: H = relu(Xe * w1 + b1)   M=C=1024, N=F=4096, K=D=1024
  gemm_bt<C, F, D, 0><<<dim3((C / 128) * (F / 128), E), 256, 0, stream>>>(
      Xe, w1t, b1, H, nullptr, nullptr, nullptr);
  // GEMM2: out = scatter((H * w2 + b2) * gate)   M=C, N=D=1024, K=F=4096
  gemm_bt<C, D, F, 1><<<dim3((C / 128) * (D / 128), E), 256, 0, stream>>>(
      H, w2t, b2, nullptr, out, slotmap, gate_slot);
}

// Round 2
// 293.752 us; speedup vs baseline: 1.2479x; 1.2479x over previous
//
#include <hip/hip_runtime.h>
#include <hip/hip_fp16.h>

typedef unsigned short ushort_t;
typedef __attribute__((ext_vector_type(8))) _Float16 half8v;
typedef __attribute__((ext_vector_type(4))) float float4v;
typedef __attribute__((ext_vector_type(8))) unsigned short ushort8v;

#define DEV_INLINE __device__ __forceinline__

DEV_INLINE ushort_t f2h_bits(float f) {
  return __half_as_ushort(__float2half(f));
}

// ---------------- router: logits, softmax max, argmax ----------------
__global__ __launch_bounds__(256) void router_kernel(
    const float* __restrict__ x, const float* __restrict__ rw,
    int* __restrict__ idx, float* __restrict__ gate)
{
  constexpr int D = 1024, E = 8;
  int token = (int)((blockIdx.x * 256 + threadIdx.x) >> 6);
  int lane = threadIdx.x & 63;
  const float* xr = x + (size_t)token * D;
  float acc[E];
#pragma unroll
  for (int e = 0; e < E; ++e) acc[e] = 0.f;
  for (int d = lane; d < D; d += 64) {
    float xv = xr[d];
#pragma unroll
    for (int e = 0; e < E; ++e) acc[e] += xv * rw[d * E + e];
  }
#pragma unroll
  for (int off = 32; off >= 1; off >>= 1) {
#pragma unroll
    for (int e = 0; e < E; ++e) acc[e] += __shfl_xor(acc[e], off);
  }
  if (lane == 0) {
    float m = acc[0]; int am = 0;
#pragma unroll
    for (int e = 1; e < E; ++e) { if (acc[e] > m) { m = acc[e]; am = e; } }
    float s = 0.f;
#pragma unroll
    for (int e = 0; e < E; ++e) s += __expf(acc[e] - m);
    idx[token] = am;
    gate[token] = 1.0f / s;   // = max(softmax)
  }
}

// ---------------- scan: token -> slot (capacity C), slot -> token ----------------
__global__ __launch_bounds__(1024) void scan_kernel(
    const int* __restrict__ idx, const float* __restrict__ gate,
    int* __restrict__ slotmap, float* __restrict__ gate_slot)
{
  constexpr int C = 1024, E = 8;
  __shared__ unsigned long long s0[1024];
  __shared__ unsigned long long s1[1024];
  int tid = threadIdx.x;
  int myidx[8];
  unsigned long long c0 = 0, c1 = 0;
#pragma unroll
  for (int j = 0; j < 8; ++j) {
    int e = idx[tid * 8 + j];
    myidx[j] = e;
    if (e < 4) c0 += 1ull << (16 * e);
    else       c1 += 1ull << (16 * (e - 4));
  }
  s0[tid] = c0; s1[tid] = c1;
  __syncthreads();
  for (int off = 1; off < 1024; off <<= 1) {
    unsigned long long b0 = 0, b1 = 0;
    if (tid >= off) { b0 = s0[tid - off]; b1 = s1[tid - off]; }
    __syncthreads();
    s0[tid] += b0; s1[tid] += b1;
    __syncthreads();
  }
  unsigned long long p0 = s0[tid] - c0, p1 = s1[tid] - c1; // exclusive prefix
  unsigned long long t0 = s0[1023], t1 = s1[1023];         // totals
  int cnt[E];
#pragma unroll
  for (int e = 0; e < 4; ++e) {
    cnt[e]     = (int)((p0 >> (16 * e)) & 0xFFFF);
    cnt[4 + e] = (int)((p1 >> (16 * e)) & 0xFFFF);
  }
#pragma unroll
  for (int j = 0; j < 8; ++j) {
    int t = tid * 8 + j;
    int e = myidx[j];
    int pos = cnt[e]++;
    if (pos < C) {
      slotmap[e * C + pos] = t;
      gate_slot[e * C + pos] = gate[t];
    }
  }
  int total[E];
#pragma unroll
  for (int e = 0; e < 4; ++e) {
    total[e]     = (int)((t0 >> (16 * e)) & 0xFFFF);
    total[4 + e] = (int)((t1 >> (16 * e)) & 0xFFFF);
  }
  for (int s = tid; s < E * C; s += 1024) {
    int e = s / C, c = s % C;
    if (c >= total[e]) { slotmap[s] = -1; gate_slot[s] = 0.f; }
  }
}

// ---------------- gather x -> Xe (fp16), zeros for empty slots ----------------
__global__ __launch_bounds__(256) void gather_kernel(
    const float* __restrict__ x, const int* __restrict__ slotmap,
    ushort_t* __restrict__ Xe)
{
  constexpr int D = 1024;
  int slot = blockIdx.x;
  int t = slotmap[slot];
  int tid = threadIdx.x;
  ushort4* dst = (ushort4*)(Xe + (size_t)slot * D);
  ushort4 o;
  if (t >= 0) {
    float4 v = ((const float4*)(x + (size_t)t * D))[tid];
    o.x = f2h_bits(v.x); o.y = f2h_bits(v.y); o.z = f2h_bits(v.z); o.w = f2h_bits(v.w);
  } else {
    o.x = 0; o.y = 0; o.z = 0; o.w = 0;
  }
  dst[tid] = o;
}

// ---------------- transpose + fp32->fp16 convert: in [R][Cc] -> out [Cc][R] ----------------
__global__ __launch_bounds__(256) void transpose_cvt(
    const float* __restrict__ in, ushort_t* __restrict__ out, int R, int Cc)
{
  __shared__ ushort_t tile[64][65];
  size_t base = (size_t)blockIdx.z * (size_t)R * (size_t)Cc;
  int c0 = blockIdx.x * 64, r0 = blockIdx.y * 64;
  int tx = threadIdx.x & 63, ty = threadIdx.x >> 6;
#pragma unroll
  for (int i = 0; i < 16; ++i) {
    int r = ty + 4 * i;
    tile[r][tx] = f2h_bits(in[base + (size_t)(r0 + r) * Cc + c0 + tx]);
  }
  __syncthreads();
#pragma unroll
  for (int i = 0; i < 2; ++i) {
    int chunk = (int)threadIdx.x + i * 256;
    int c = chunk >> 3, g = chunk & 7;
    ushort8v v;
#pragma unroll
    for (int j = 0; j < 8; ++j) v[j] = tile[8 * g + j][c];
    *(ushort8v*)(out + base + (size_t)(c0 + c) * R + r0 + 8 * g) = v;
  }
}

// =====================================================================
// 8-phase counted-vmcnt grouped GEMM:  C = A(f16,[M][K]) * Bt(f16,[N][K])^T
// 512 threads = 8 waves (2M x 4N). BK=64 split in two k-halves.
// LDS XOR-swizzle (16B unit ^= (row>>1)&3), applied on the global SOURCE
// (linear global_load_lds dest) and on the ds_read address (same involution).
// MODE 0: H = relu(C + b1) -> fp16 [E][M][N]
// MODE 1: out[token] = (C + b2) * gate, scattered via slotmap
// =====================================================================
#define BARRIER() asm volatile("s_barrier" ::: "memory")

#define READ_B(b,kh) do { _Pragma("unroll") \
  for (int j = 0; j < 4; ++j) \
    bfr[j] = *(const half8v*)&lds[b][AELEM + (kh)*(BN*32) + (brow + j*16)*32 + axor]; } while(0)

#define READ_A(b,kh,mg) do { _Pragma("unroll") \
  for (int i = 0; i < MG; ++i) \
    afr[i] = *(const half8v*)&lds[b][(kh)*(BM*32) + (arow + ((mg)*MG+i)*16)*32 + axor]; } while(0)

#define DO_MFMA(mg) do { __builtin_amdgcn_s_setprio(1); \
  _Pragma("unroll") for (int i = 0; i < MG; ++i) { \
  _Pragma("unroll") for (int j = 0; j < 4; ++j) \
    acc[(mg)*MG+i][j] = __builtin_amdgcn_mfma_f32_16x16x32_f16(afr[i], bfr[j], acc[(mg)*MG+i][j], 0, 0, 0); } \
  __builtin_amdgcn_s_setprio(0); } while(0)

template<int M_, int N_, int K_, int BM, int BN, int MODE>
__global__ __launch_bounds__(512, 2) void gemm8p(
    const ushort_t* __restrict__ A, const ushort_t* __restrict__ Bt,
    const float* __restrict__ bias,
    ushort_t* __restrict__ Hout, float* __restrict__ outp,
    const int* __restrict__ slotmap, const float* __restrict__ gate_slot)
{
  constexpr int NTM = M_ / BM, NTN = N_ / BN;
  constexpr int WPB = NTM * NTN;     // blocks per expert
  constexpr int NWG = 8 * WPB;
  constexpr int M_REP = BM / 32;     // m-frags per wave
  constexpr int MG = M_REP / 2;      // m-frags per phase
  constexpr int LA = BM / 128;       // loads/thread per A k-half
  constexpr int LB = BN / 128;
  constexpr int VA = LA + LB;        // vmcnt allowance = 2 half-tiles in flight
  constexpr int AELEM = BM * 64;
  constexpr int BELEM = BN * 64;
  constexpr int NT = K_ / 64;

  __shared__ __attribute__((aligned(16))) ushort_t lds[2][AELEM + BELEM];

  // bijective XCD swizzle: consecutive swz share expert+B-panel on one XCD
  const int bid = blockIdx.x;
  constexpr int CPX = NWG / 8;
  const int swz = (bid & 7) * CPX + (bid >> 3);
  const int e  = swz / WPB;
  const int rr = swz % WPB;
  const int nt = rr / NTM;
  const int mt = rr % NTM;

  const ushort_t* Ae = A  + (size_t)e * M_ * K_ + (size_t)(mt * BM) * K_;
  const ushort_t* Be = Bt + (size_t)e * N_ * K_ + (size_t)(nt * BN) * K_;
  const int tid  = threadIdx.x;
  const int lane = tid & 63;
  const int w    = tid >> 6;
  const int wr   = w >> 2;   // 0..1
  const int wc   = w & 3;    // 0..3

  const int l15  = lane & 15;
  const int axor = ((lane >> 4) ^ ((l15 >> 1) & 3)) << 3;   // swizzled 16B unit
  const int arow = wr * (BM / 2) + l15;
  const int brow = wc * 64 + l15;

  // stage one k-half (32 k-cols) of A or B into buf b, linear LDS dest,
  // inverse-swizzled global source.
  auto stageA = [&](int b, int kh, int kbase) {
#pragma unroll
    for (int i = 0; i < LA; ++i) {
      int unit = i * 512 + tid;
      int row  = unit >> 2;
      int ul   = (unit & 3) ^ ((row >> 1) & 3);
      const ushort_t* src = Ae + (size_t)row * K_ + kbase + kh * 32 + ul * 8;
      __builtin_amdgcn_global_load_lds(
          (const __attribute__((address_space(1))) void*)src,
          (__attribute__((address_space(3))) void*)(&lds[b][kh * (BM * 32)] + (i * 8 + w) * 512),
          16, 0, 0);
    }
  };
  auto stageB = [&](int b, int kh, int kbase) {
#pragma unroll
    for (int i = 0; i < LB; ++i) {
      int unit = i * 512 + tid;
      int row  = unit >> 2;
      int ul   = (unit & 3) ^ ((row >> 1) & 3);
      const ushort_t* src = Be + (size_t)row * K_ + kbase + kh * 32 + ul * 8;
      __builtin_amdgcn_global_load_lds(
          (const __attribute__((address_space(1))) void*)src,
          (__attribute__((address_space(3))) void*)(&lds[b][AELEM + kh * (BN * 32)] + (i * 8 + w) * 512),
          16, 0, 0);
    }
  };
  auto WAITVA = [&]() {
    if constexpr (VA == 4)      asm volatile("s_waitcnt vmcnt(4)" ::: "memory");
    else if constexpr (VA == 3) asm volatile("s_waitcnt vmcnt(3)" ::: "memory");
    else                        asm volatile("s_waitcnt vmcnt(2)" ::: "memory");
  };

  float4v acc[M_REP][4] = {};
  half8v bfr[4], afr[MG];

  // prologue: tile 0, issue all 4 half-tiles, wait first pair
  stageA(0, 0, 0); stageB(0, 0, 0); stageA(0, 1, 0); stageB(0, 1, 0);
  WAITVA(); BARRIER();

  for (int t = 0; t < NT - 1; ++t) {
    const int b = t & 1, nb = b ^ 1;
    const int kn = (t + 1) * 64;
    // ph1: kh0 / m-group0 ; prefetch A-kh0(t+1)
    READ_B(b, 0); READ_A(b, 0, 0);
    stageA(nb, 0, kn);
    BARRIER(); DO_MFMA(0); BARRIER();
    // ph2: kh0 / m-group1 ; prefetch B-kh0(t+1) ; counted wait guards kh1(t)
    READ_A(b, 0, 1);
    stageB(nb, 0, kn);
    BARRIER(); DO_MFMA(1); WAITVA(); BARRIER();
    // ph3: kh1 / m-group0 ; prefetch A-kh1(t+1)
    READ_B(b, 1); READ_A(b, 1, 0);
    stageA(nb, 1, kn);
    BARRIER(); DO_MFMA(0); BARRIER();
    // ph4: kh1 / m-group1 ; prefetch B-kh1(t+1) ; counted wait guards kh0(t+1)
    READ_A(b, 1, 1);
    stageB(nb, 1, kn);
    BARRIER(); DO_MFMA(1); WAITVA(); BARRIER();
  }
  {  // epilogue tile (no prefetch; drain before kh1)
    const int b = (NT - 1) & 1;
    READ_B(b, 0); READ_A(b, 0, 0);
    BARRIER(); DO_MFMA(0); BARRIER();
    READ_A(b, 0, 1);
    BARRIER(); DO_MFMA(1);
    asm volatile("s_waitcnt vmcnt(0)" ::: "memory");
    BARRIER();
    READ_B(b, 1); READ_A(b, 1, 0);
    BARRIER(); DO_MFMA(0); BARRIER();
    READ_A(b, 1, 1);
    BARRIER(); DO_MFMA(1); BARRIER();
  }

  // ---- epilogue: C/D frag mapping col = lane&15, row = (lane>>4)*4 + q ----
  const int lr4 = (lane >> 4) * 4;
  const int mbase0 = mt * BM + wr * (BM / 2);
  const int nbase  = nt * BN + wc * 64;

  float bv[4];
#pragma unroll
  for (int j = 0; j < 4; ++j) bv[j] = bias[e * N_ + nbase + j * 16 + l15];

  if (MODE == 0) {
    ushort_t* He = Hout + (size_t)e * M_ * N_;
#pragma unroll
    for (int i = 0; i < M_REP; ++i) {
#pragma unroll
      for (int q = 0; q < 4; ++q) {
        int m = mbase0 + i * 16 + lr4 + q;
#pragma unroll
        for (int j = 0; j < 4; ++j) {
          float v = acc[i][j][q] + bv[j];
          v = v > 0.f ? v : 0.f;
          He[(size_t)m * N_ + nbase + j * 16 + l15] = f2h_bits(v);
        }
      }
    }
  } else {
#pragma unroll
    for (int i = 0; i < M_REP; ++i) {
#pragma unroll
      for (int q = 0; q < 4; ++q) {
        int slot = e * M_ + mbase0 + i * 16 + lr4 + q;
        int tkn = slotmap[slot];
        if (tkn < 0) continue;
        float gt = gate_slot[slot];
#pragma unroll
        for (int j = 0; j < 4; ++j) {
          outp[(size_t)tkn * N_ + nbase + j * 16 + l15] = (acc[i][j][q] + bv[j]) * gt;
        }
      }
    }
  }
}

extern "C" void kernel_launch(void* const* d_in, const int* in_sizes, int n_in,
                              void* d_out, int out_size, void* d_ws, size_t ws_size,
                              hipStream_t stream)
{
  const float* x  = (const float*)d_in[0];
  const float* rw = (const float*)d_in[1];
  const float* w1 = (const float*)d_in[2];
  const float* b1 = (const float*)d_in[3];
  const float* w2 = (const float*)d_in[4];
  const float* b2 = (const float*)d_in[5];
  float* out = (float*)d_out;

  constexpr int D = 1024, E = 8, F = 4096, T = 8192, C = 1024;

  char* p = (char*)d_ws;
  auto take = [&](size_t bytes) { char* r = p; p += (bytes + 255) & ~(size_t)255; return r; };
  ushort_t* w1t = (ushort_t*)take((size_t)E * D * F * 2);  // [E][F][D] f16
  ushort_t* w2t = (ushort_t*)take((size_t)E * F * D * 2);  // [E][D][F] f16
  ushort_t* Xe  = (ushort_t*)take((size_t)E * C * D * 2);  // [E][C][D] f16
  ushort_t* H   = (ushort_t*)take((size_t)E * C * F * 2);  // [E][C][F] f16
  int*      idx = (int*)take((size_t)T * 4);
  float*   gate = (float*)take((size_t)T * 4);
  int*  slotmap = (int*)take((size_t)E * C * 4);
  float* gate_slot = (float*)take((size_t)E * C * 4);

  router_kernel<<<T / 4, 256, 0, stream>>>(x, rw, idx, gate);
  scan_kernel<<<1, 1024, 0, stream>>>(idx, gate, slotmap, gate_slot);
  gather_kernel<<<E * C, 256, 0, stream>>>(x, slotmap, Xe);
  transpose_cvt<<<dim3(F / 64, D / 64, E), 256, 0, stream>>>(w1, w1t, D, F); // [D][F]->[F][D]
  transpose_cvt<<<dim3(D / 64, F / 64, E), 256, 0, stream>>>(w2, w2t, F, D); // [F][D]->[D][F]
  hipMemsetAsync(d_out, 0, (size_t)out_size * sizeof(float), stream);
  // GEMM1: H = relu(Xe * w1 + b1)   M=1024, N=4096, K=1024, 256x256 tiles -> 512 blocks
  gemm8p<C, F, D, 256, 256, 0><<<512, 512, 0, stream>>>(
      Xe, w1t, b1, H, nullptr, nullptr, nullptr);
  // GEMM2: out = scatter((H * w2 + b2) * gate)   M=1024, N=1024, K=4096, 128x256 tiles -> 256 blocks
  gemm8p<C, D, F, 128, 256, 1><<<256, 512, 0, stream>>>(
      H, w2t, b2, nullptr, out, slotmap, gate_slot);
}